// Round 6
// baseline (116.827 us; speedup 1.0000x reference)
//
#include <hip/hip_runtime.h>
#include <cstdint>
#include <cstddef>

#define L_SEQ 2048
#define E_DIM 512
#define B_SZ 2
#define WIN 64
#define SCALE_QK 0.044194173824159216f  // 1/sqrt(512)

typedef __attribute__((ext_vector_type(8))) short short8;
typedef __attribute__((ext_vector_type(4))) float floatx4;

__device__ __forceinline__ unsigned short f2bf(float f) {
    unsigned int u = __float_as_uint(f);
    u += 0x7FFFu + ((u >> 16) & 1u);
    return (unsigned short)(u >> 16);
}

// pack 8 fp32 -> 8 bf16 (RNE) via v_cvt_pk_bf16_f32 (gfx950; measured-working
// inline asm per learn_hip m240).  D[15:0]=bf16(S0), D[31:16]=bf16(S1) ->
// memory element order matches consecutive columns.
__device__ __forceinline__ uint4 pk8(const float4 lo, const float4 hi) {
    uint4 r;
    asm("v_cvt_pk_bf16_f32 %0, %1, %2" : "=v"(r.x) : "v"(lo.x), "v"(lo.y));
    asm("v_cvt_pk_bf16_f32 %0, %1, %2" : "=v"(r.y) : "v"(lo.z), "v"(lo.w));
    asm("v_cvt_pk_bf16_f32 %0, %1, %2" : "=v"(r.z) : "v"(hi.x), "v"(hi.y));
    asm("v_cvt_pk_bf16_f32 %0, %1, %2" : "=v"(r.w) : "v"(hi.z), "v"(hi.w));
    return r;
}

// ---------------- QKV projection with INLINE fp32->bf16 conversion ----------
// C[m,n] = sum_k X[m,k] W[n,k] + bias[n].  Reads x / W as fp32 directly and
// converts in-register during staging (cvt kernel + xb/wb buffers eliminated:
// 2 fewer launch boundaries, 12 MB less workspace traffic; q/k/vt outputs are
// bit-identical to the previous f2bf pipeline since cvt_pk is RNE).
// 64x64 tile, BK=64, reg double-buffer (R0-R3 proven structure).
// z==0 -> q[m][n], z==1 -> k[m][n], z==2 -> vT[n][m] (token-contiguous rows).
// grid (64,8,3) = 1536 blocks.
#define ALD 72   // LDS row stride (bf16): 36 dw -> 2-way conflicts only per 16-lane phase
__global__ __launch_bounds__(256) void qkv_gemm(
    const float* __restrict__ x,    // 4096 x 512 fp32
    const float* __restrict__ Wq, const float* __restrict__ Wk, const float* __restrict__ Wv,
    const float* __restrict__ bq, const float* __restrict__ bk, const float* __restrict__ bv,
    unsigned short* __restrict__ q, unsigned short* __restrict__ k,
    unsigned short* __restrict__ vt)
{
    __shared__ __align__(16) unsigned short As[64 * ALD];   // 9216 B (aliased by epilogue)
    __shared__ __align__(16) unsigned short Bs[64 * ALD];

    const int t = threadIdx.x;
    const int w = t >> 6, l = t & 63;
    const int m0 = blockIdx.x * 64, n0 = blockIdx.y * 64, z = blockIdx.z;
    const float* W    = (z == 0) ? Wq : ((z == 1) ? Wk : Wv);
    const float* bias = (z == 0) ? bq : ((z == 1) ? bk : bv);

    floatx4 acc[2][2] = {};
    const int wm = (w >> 1) * 32, wn = (w & 1) * 32;
    const int fr = l & 15, fq = l >> 4, fk = fq * 8;

    const int srow = t >> 2, scol = (t & 3) * 16;           // 16 cols per thread
    const float* gA = x + (size_t)(m0 + srow) * 512 + scol;
    const float* gB = W + (size_t)(n0 + srow) * 512 + scol;

    float4 fa0 = *(const float4*)(gA);      float4 fa1 = *(const float4*)(gA + 4);
    float4 fa2 = *(const float4*)(gA + 8);  float4 fa3 = *(const float4*)(gA + 12);
    float4 fb0 = *(const float4*)(gB);      float4 fb1 = *(const float4*)(gB + 4);
    float4 fb2 = *(const float4*)(gB + 8);  float4 fb3 = *(const float4*)(gB + 12);

    for (int it = 0; it < 8; it++) {
        *(uint4*)&As[srow * ALD + scol]     = pk8(fa0, fa1);
        *(uint4*)&As[srow * ALD + scol + 8] = pk8(fa2, fa3);
        *(uint4*)&Bs[srow * ALD + scol]     = pk8(fb0, fb1);
        *(uint4*)&Bs[srow * ALD + scol + 8] = pk8(fb2, fb3);
        __syncthreads();
        if (it < 7) {                       // prefetch next K-slice; overlaps compute below
            int kk = (it + 1) * 64;
            fa0 = *(const float4*)(gA + kk);      fa1 = *(const float4*)(gA + kk + 4);
            fa2 = *(const float4*)(gA + kk + 8);  fa3 = *(const float4*)(gA + kk + 12);
            fb0 = *(const float4*)(gB + kk);      fb1 = *(const float4*)(gB + kk + 4);
            fb2 = *(const float4*)(gB + kk + 8);  fb3 = *(const float4*)(gB + kk + 12);
        }
        short8 a[2][2], bf[2][2];
#pragma unroll
        for (int i = 0; i < 2; i++)
#pragma unroll
            for (int kh = 0; kh < 2; kh++)
                a[i][kh] = *(const short8*)&As[(wm + i * 16 + fr) * ALD + kh * 32 + fk];
#pragma unroll
        for (int j = 0; j < 2; j++)
#pragma unroll
            for (int kh = 0; kh < 2; kh++)
                bf[j][kh] = *(const short8*)&Bs[(wn + j * 16 + fr) * ALD + kh * 32 + fk];
#pragma unroll
        for (int kh = 0; kh < 2; kh++)
#pragma unroll
            for (int i = 0; i < 2; i++)
#pragma unroll
                for (int j = 0; j < 2; j++)
                    acc[i][j] = __builtin_amdgcn_mfma_f32_16x16x32_bf16(a[i][kh], bf[j][kh], acc[i][j], 0, 0, 0);
        __syncthreads();
    }

    // epilogue: frags (C/D: col=lane&15, row=(lane>>4)*4+reg) -> LDS tile -> coalesced stores
    unsigned short* Tl = As;   // 64 x ALD alias
    float bv_[2];
#pragma unroll
    for (int j = 0; j < 2; j++) bv_[j] = bias[n0 + wn + j * 16 + fr];

    if (z < 2) {
#pragma unroll
        for (int i = 0; i < 2; i++)
#pragma unroll
            for (int j = 0; j < 2; j++)
#pragma unroll
                for (int r = 0; r < 4; r++)
                    Tl[(wm + i * 16 + fq * 4 + r) * ALD + wn + j * 16 + fr] =
                        f2bf(acc[i][j][r] + bv_[j]);
    } else {
#pragma unroll
        for (int i = 0; i < 2; i++)
#pragma unroll
            for (int j = 0; j < 2; j++)
#pragma unroll
                for (int r = 0; r < 4; r++)
                    Tl[(wn + j * 16 + fr) * ALD + wm + i * 16 + fq * 4 + r] =
                        f2bf(acc[i][j][r] + bv_[j]);
    }
    __syncthreads();

    const int tr = t >> 2, tc = (t & 3) * 16;
    uint4 v0 = *(const uint4*)&Tl[tr * ALD + tc];
    uint4 v1 = *(const uint4*)&Tl[tr * ALD + tc + 8];
    if (z < 2) {
        unsigned short* out = (z == 0) ? q : k;
        *(uint4*)&out[(size_t)(m0 + tr) * 512 + n0 + tc]     = v0;
        *(uint4*)&out[(size_t)(m0 + tr) * 512 + n0 + tc + 8] = v1;
    } else {
        *(uint4*)&vt[(size_t)(n0 + tr) * 4096 + m0 + tc]     = v0;
        *(uint4*)&vt[(size_t)(n0 + tr) * 4096 + m0 + tc + 8] = v1;
    }
}

// ---------------- fused attention: 8 waves per 16-row Q-tile ----------------
// (unchanged from R3/R4 — passed twice)
// grid (128 Qtiles, 2 b), 512 threads. Wave w computes score n-tile w (wave 0
// also tile 8) into a shared fp32 LDS S-tile; one barrier; every wave
// redundantly computes the row-softmax from LDS; wave w runs PV for E-cols
// [64w, 64w+64).  All global loads unconditional (clamped addresses) and
// batched; masking done on values (-1e30 -> P=0).
#define SLD 164   // LDS row stride (fp32): 164%32=4 -> 2-way conflicts max on row reads
__global__ __launch_bounds__(512) void attn_fused(
    const unsigned short* __restrict__ qb, const unsigned short* __restrict__ kb,
    const unsigned short* __restrict__ vt, float* __restrict__ out)
{
    __shared__ __align__(16) float Sl[16 * SLD];   // 10.5 KB

    const int t = threadIdx.x;
    const int w = t >> 6, l = t & 63;
    const int fr = l & 15, fq = l >> 4;
    const int Q0 = blockIdx.x * 16;
    const int b  = blockIdx.y;
    const int R0 = Q0 - WIN;

    // ---- scores: wave w handles n-tile(s) {w, w+8} (only wave 0 gets a second)
    {
        const unsigned short* qrow = qb + (size_t)(b * L_SEQ + Q0 + fr) * 512 + fq * 8;
        short8 qf[16];
#pragma unroll
        for (int ks = 0; ks < 16; ks++) qf[ks] = *(const short8*)(qrow + ks * 32);

        for (int nt = w; nt < 9; nt += 8) {
            const int tok = R0 + nt * 16 + fr;
            const bool kvalid = (tok >= 0) && (tok < L_SEQ);
            const int tokc = min(max(tok, 0), L_SEQ - 1);        // clamped: always a real row
            const unsigned short* krow = kb + (size_t)(b * L_SEQ + tokc) * 512 + fq * 8;

            floatx4 acc0 = {}, acc1 = {};                        // 2 chains (8-deep, not 16)
            short8 bfr[8];
#pragma unroll
            for (int ks = 0; ks < 8; ks++) bfr[ks] = *(const short8*)(krow + ks * 32);
#pragma unroll
            for (int ks = 0; ks < 8; ks++)
                acc0 = __builtin_amdgcn_mfma_f32_16x16x32_bf16(qf[ks], bfr[ks], acc0, 0, 0, 0);
#pragma unroll
            for (int ks = 0; ks < 8; ks++) bfr[ks] = *(const short8*)(krow + (8 + ks) * 32);
#pragma unroll
            for (int ks = 0; ks < 8; ks++)
                acc1 = __builtin_amdgcn_mfma_f32_16x16x32_bf16(qf[8 + ks], bfr[ks], acc1, 0, 0, 0);

            const int jg = nt * 16 + fr;
#pragma unroll
            for (int r = 0; r < 4; r++) {
                int qq = fq * 4 + r;    // C/D layout: col=lane&15, row=(lane>>4)*4+r
                bool valid = kvalid && (jg >= qq) && (jg <= qq + 128);
                Sl[qq * SLD + jg] = valid ? (acc0[r] + acc1[r]) * SCALE_QK : -1e30f;
            }
        }
    }
    __syncthreads();

    // ---- softmax (per-wave redundant): lane covers row fr, cols fq*8 + ks*32 + j
    const float* Srow = &Sl[fr * SLD + fq * 8];
    float sv[5][8];
#pragma unroll
    for (int ks = 0; ks < 5; ks++) {
        float4 u0 = *(const float4*)(Srow + ks * 32);
        float4 u1 = *(const float4*)(Srow + ks * 32 + 4);
        sv[ks][0] = u0.x; sv[ks][1] = u0.y; sv[ks][2] = u0.z; sv[ks][3] = u0.w;
        sv[ks][4] = u1.x; sv[ks][5] = u1.y; sv[ks][6] = u1.z; sv[ks][7] = u1.w;
    }
    if (fq >= 2) {                    // cols 144..159: unwritten pad
#pragma unroll
        for (int j = 0; j < 8; j++) sv[4][j] = -1e30f;
    }
    float m = -1e30f;
#pragma unroll
    for (int ks = 0; ks < 5; ks++)
#pragma unroll
        for (int j = 0; j < 8; j++) m = fmaxf(m, sv[ks][j]);
    m = fmaxf(m, __shfl_xor(m, 16));
    m = fmaxf(m, __shfl_xor(m, 32));
    float sum = 0.f;
#pragma unroll
    for (int ks = 0; ks < 5; ks++)
#pragma unroll
        for (int j = 0; j < 8; j++) { float e = __expf(sv[ks][j] - m); sv[ks][j] = e; sum += e; }
    sum += __shfl_xor(sum, 16);
    sum += __shfl_xor(sum, 32);
    float inv = 1.f / sum;

    short8 a[5];     // P in A-frag layout: row fr, k-pos fq*8+j within 32-slice ks
#pragma unroll
    for (int ks = 0; ks < 5; ks++)
#pragma unroll
        for (int j = 0; j < 8; j++) a[ks][j] = (short)f2bf(sv[ks][j] * inv);

    // ---- PV: wave w owns E-cols [64w, 64w+64); loads clamped + batched (P=0 masks OOB)
    const int EC = w * 64;
    int tkc[5];
#pragma unroll
    for (int ks = 0; ks < 5; ks++) {
        int tok0 = R0 + ks * 32 + fq * 8;              // mod-8 aligned granule
        tkc[ks] = min(max(tok0, 0), L_SEQ - 8);        // clamp keeps 16B alignment
    }
    floatx4 oa[4] = {};
#pragma unroll
    for (int et = 0; et < 4; et++) {
        const unsigned short* vrow = vt + (size_t)(EC + et * 16 + fr) * 4096 + b * L_SEQ;
        short8 vfr[5];
#pragma unroll
        for (int ks = 0; ks < 5; ks++) vfr[ks] = *(const short8*)(vrow + tkc[ks]);
#pragma unroll
        for (int ks = 0; ks < 5; ks++)
            oa[et] = __builtin_amdgcn_mfma_f32_16x16x32_bf16(a[ks], vfr[ks], oa[et], 0, 0, 0);
    }

    float* op = out + (size_t)b * L_SEQ * E_DIM;
#pragma unroll
    for (int et = 0; et < 4; et++)
#pragma unroll
        for (int r = 0; r < 4; r++)
            op[(size_t)(Q0 + fq * 4 + r) * 512 + EC + et * 16 + fr] = oa[et][r];
}

// ---------------- launch ----------------
extern "C" void kernel_launch(void* const* d_in, const int* in_sizes, int n_in,
                              void* d_out, int out_size, void* d_ws, size_t ws_size,
                              hipStream_t stream)
{
    const float* x  = (const float*)d_in[0];
    const float* Wq = (const float*)d_in[1];
    const float* bq = (const float*)d_in[2];
    const float* Wk = (const float*)d_in[3];
    const float* bk = (const float*)d_in[4];
    const float* Wv = (const float*)d_in[5];
    const float* bv = (const float*)d_in[6];
    float* out = (float*)d_out;

    char* ws = (char*)d_ws;
    unsigned short* qb = (unsigned short*)(ws);                  // 4 MB bf16 q
    unsigned short* kb = (unsigned short*)(ws + 4194304);        // 4 MB bf16 k
    unsigned short* vt = (unsigned short*)(ws + 8388608);        // 4 MB bf16 v^T [e][tok]

    qkv_gemm<<<dim3(64, 8, 3), 256, 0, stream>>>(x, Wq, Wk, Wv, bq, bk, bv, qb, kb, vt);
    attn_fused<<<dim3(128, 2), 512, 0, stream>>>(qb, kb, vt, out);
}

// Round 7
// 115.203 us; speedup vs baseline: 1.0141x; 1.0141x over previous
//
#include <hip/hip_runtime.h>
#include <cstdint>
#include <cstddef>

#define L_SEQ 2048
#define E_DIM 512
#define B_SZ 2
#define WIN 64
#define SCALE_QK 0.044194173824159216f  // 1/sqrt(512)

typedef __attribute__((ext_vector_type(8))) short short8;
typedef __attribute__((ext_vector_type(4))) float floatx4;

__device__ __forceinline__ unsigned short f2bf(float f) {
    unsigned int u = __float_as_uint(f);
    u += 0x7FFFu + ((u >> 16) & 1u);
    return (unsigned short)(u >> 16);
}

// pack 8 fp32 -> 8 bf16 (RNE) via v_cvt_pk_bf16_f32 (gfx950; verified passing in R6).
__device__ __forceinline__ uint4 pk8(const float4 lo, const float4 hi) {
    uint4 r;
    asm("v_cvt_pk_bf16_f32 %0, %1, %2" : "=v"(r.x) : "v"(lo.x), "v"(lo.y));
    asm("v_cvt_pk_bf16_f32 %0, %1, %2" : "=v"(r.y) : "v"(lo.z), "v"(lo.w));
    asm("v_cvt_pk_bf16_f32 %0, %1, %2" : "=v"(r.z) : "v"(hi.x), "v"(hi.y));
    asm("v_cvt_pk_bf16_f32 %0, %1, %2" : "=v"(r.w) : "v"(hi.z), "v"(hi.w));
    return r;
}

// load 16 fp32 cols and convert immediately to 2 uint4 of bf16 — fp32
// temporaries die here, so prefetch register footprint = 16 VGPRs (same as
// the R3 bf16 kernel), NOT 32 (the R6 regression: fp32 float4s held live
// across the MFMA section).
__device__ __forceinline__ void ld16cvt(const float* g, uint4& r0, uint4& r1) {
    float4 f0 = *(const float4*)(g);
    float4 f1 = *(const float4*)(g + 4);
    float4 f2 = *(const float4*)(g + 8);
    float4 f3 = *(const float4*)(g + 12);
    r0 = pk8(f0, f1);
    r1 = pk8(f2, f3);
}

// ---------------- QKV projection with INLINE fp32->bf16 conversion ----------
// C[m,n] = sum_k X[m,k] W[n,k] + bias[n].  Reads x / W fp32, converts to bf16
// right after load (RNE => outputs bit-identical to the cvt-kernel pipeline).
// 64x64 tile, BK=64, reg double-buffer (R0-R3 proven structure; prefetch regs
// bf16-width as in R3).  z==0 -> q, z==1 -> k, z==2 -> vT[n][m].
// grid (64,8,3) = 1536 blocks.
#define ALD 72   // LDS row stride (bf16): 36 dw -> 2-way conflicts only per 16-lane phase
__global__ __launch_bounds__(256) void qkv_gemm(
    const float* __restrict__ x,    // 4096 x 512 fp32
    const float* __restrict__ Wq, const float* __restrict__ Wk, const float* __restrict__ Wv,
    const float* __restrict__ bq, const float* __restrict__ bk, const float* __restrict__ bv,
    unsigned short* __restrict__ q, unsigned short* __restrict__ k,
    unsigned short* __restrict__ vt)
{
    __shared__ __align__(16) unsigned short As[64 * ALD];   // 9216 B (aliased by epilogue)
    __shared__ __align__(16) unsigned short Bs[64 * ALD];

    const int t = threadIdx.x;
    const int w = t >> 6, l = t & 63;
    const int m0 = blockIdx.x * 64, n0 = blockIdx.y * 64, z = blockIdx.z;
    const float* W    = (z == 0) ? Wq : ((z == 1) ? Wk : Wv);
    const float* bias = (z == 0) ? bq : ((z == 1) ? bk : bv);

    floatx4 acc[2][2] = {};
    const int wm = (w >> 1) * 32, wn = (w & 1) * 32;
    const int fr = l & 15, fq = l >> 4, fk = fq * 8;

    const int srow = t >> 2, scol = (t & 3) * 16;           // 16 cols per thread
    const float* gA = x + (size_t)(m0 + srow) * 512 + scol;
    const float* gB = W + (size_t)(n0 + srow) * 512 + scol;

    uint4 ra0, ra1, rb0, rb1;
    ld16cvt(gA, ra0, ra1);
    ld16cvt(gB, rb0, rb1);

    for (int it = 0; it < 8; it++) {
        *(uint4*)&As[srow * ALD + scol]     = ra0;
        *(uint4*)&As[srow * ALD + scol + 8] = ra1;
        *(uint4*)&Bs[srow * ALD + scol]     = rb0;
        *(uint4*)&Bs[srow * ALD + scol + 8] = rb1;
        __syncthreads();
        if (it < 7) {                       // prefetch next K-slice (bf16 regs; fp32 dies in ld16cvt)
            int kk = (it + 1) * 64;
            ld16cvt(gA + kk, ra0, ra1);
            ld16cvt(gB + kk, rb0, rb1);
        }
        short8 a[2][2], bf[2][2];
#pragma unroll
        for (int i = 0; i < 2; i++)
#pragma unroll
            for (int kh = 0; kh < 2; kh++)
                a[i][kh] = *(const short8*)&As[(wm + i * 16 + fr) * ALD + kh * 32 + fk];
#pragma unroll
        for (int j = 0; j < 2; j++)
#pragma unroll
            for (int kh = 0; kh < 2; kh++)
                bf[j][kh] = *(const short8*)&Bs[(wn + j * 16 + fr) * ALD + kh * 32 + fk];
#pragma unroll
        for (int kh = 0; kh < 2; kh++)
#pragma unroll
            for (int i = 0; i < 2; i++)
#pragma unroll
                for (int j = 0; j < 2; j++)
                    acc[i][j] = __builtin_amdgcn_mfma_f32_16x16x32_bf16(a[i][kh], bf[j][kh], acc[i][j], 0, 0, 0);
        __syncthreads();
    }

    // epilogue: frags (C/D: col=lane&15, row=(lane>>4)*4+reg) -> LDS tile -> coalesced stores
    unsigned short* Tl = As;   // 64 x ALD alias
    float bv_[2];
#pragma unroll
    for (int j = 0; j < 2; j++) bv_[j] = bias[n0 + wn + j * 16 + fr];

    if (z < 2) {
#pragma unroll
        for (int i = 0; i < 2; i++)
#pragma unroll
            for (int j = 0; j < 2; j++)
#pragma unroll
                for (int r = 0; r < 4; r++)
                    Tl[(wm + i * 16 + fq * 4 + r) * ALD + wn + j * 16 + fr] =
                        f2bf(acc[i][j][r] + bv_[j]);
    } else {
#pragma unroll
        for (int i = 0; i < 2; i++)
#pragma unroll
            for (int j = 0; j < 2; j++)
#pragma unroll
                for (int r = 0; r < 4; r++)
                    Tl[(wn + j * 16 + fr) * ALD + wm + i * 16 + fq * 4 + r] =
                        f2bf(acc[i][j][r] + bv_[j]);
    }
    __syncthreads();

    const int tr = t >> 2, tc = (t & 3) * 16;
    uint4 v0 = *(const uint4*)&Tl[tr * ALD + tc];
    uint4 v1 = *(const uint4*)&Tl[tr * ALD + tc + 8];
    if (z < 2) {
        unsigned short* out = (z == 0) ? q : k;
        *(uint4*)&out[(size_t)(m0 + tr) * 512 + n0 + tc]     = v0;
        *(uint4*)&out[(size_t)(m0 + tr) * 512 + n0 + tc + 8] = v1;
    } else {
        *(uint4*)&vt[(size_t)(n0 + tr) * 4096 + m0 + tc]     = v0;
        *(uint4*)&vt[(size_t)(n0 + tr) * 4096 + m0 + tc + 8] = v1;
    }
}

// ---------------- fused attention: 8 waves per 16-row Q-tile ----------------
// (unchanged — passed R3/R4/R6)
#define SLD 164   // LDS row stride (fp32): 164%32=4 -> 2-way conflicts max on row reads
__global__ __launch_bounds__(512) void attn_fused(
    const unsigned short* __restrict__ qb, const unsigned short* __restrict__ kb,
    const unsigned short* __restrict__ vt, float* __restrict__ out)
{
    __shared__ __align__(16) float Sl[16 * SLD];   // 10.5 KB

    const int t = threadIdx.x;
    const int w = t >> 6, l = t & 63;
    const int fr = l & 15, fq = l >> 4;
    const int Q0 = blockIdx.x * 16;
    const int b  = blockIdx.y;
    const int R0 = Q0 - WIN;

    // ---- scores: wave w handles n-tile(s) {w, w+8} (only wave 0 gets a second)
    {
        const unsigned short* qrow = qb + (size_t)(b * L_SEQ + Q0 + fr) * 512 + fq * 8;
        short8 qf[16];
#pragma unroll
        for (int ks = 0; ks < 16; ks++) qf[ks] = *(const short8*)(qrow + ks * 32);

        for (int nt = w; nt < 9; nt += 8) {
            const int tok = R0 + nt * 16 + fr;
            const bool kvalid = (tok >= 0) && (tok < L_SEQ);
            const int tokc = min(max(tok, 0), L_SEQ - 1);        // clamped: always a real row
            const unsigned short* krow = kb + (size_t)(b * L_SEQ + tokc) * 512 + fq * 8;

            floatx4 acc0 = {}, acc1 = {};                        // 2 chains (8-deep, not 16)
            short8 bfr[8];
#pragma unroll
            for (int ks = 0; ks < 8; ks++) bfr[ks] = *(const short8*)(krow + ks * 32);
#pragma unroll
            for (int ks = 0; ks < 8; ks++)
                acc0 = __builtin_amdgcn_mfma_f32_16x16x32_bf16(qf[ks], bfr[ks], acc0, 0, 0, 0);
#pragma unroll
            for (int ks = 0; ks < 8; ks++) bfr[ks] = *(const short8*)(krow + (8 + ks) * 32);
#pragma unroll
            for (int ks = 0; ks < 8; ks++)
                acc1 = __builtin_amdgcn_mfma_f32_16x16x32_bf16(qf[8 + ks], bfr[ks], acc1, 0, 0, 0);

            const int jg = nt * 16 + fr;
#pragma unroll
            for (int r = 0; r < 4; r++) {
                int qq = fq * 4 + r;    // C/D layout: col=lane&15, row=(lane>>4)*4+r
                bool valid = kvalid && (jg >= qq) && (jg <= qq + 128);
                Sl[qq * SLD + jg] = valid ? (acc0[r] + acc1[r]) * SCALE_QK : -1e30f;
            }
        }
    }
    __syncthreads();

    // ---- softmax (per-wave redundant): lane covers row fr, cols fq*8 + ks*32 + j
    const float* Srow = &Sl[fr * SLD + fq * 8];
    float sv[5][8];
#pragma unroll
    for (int ks = 0; ks < 5; ks++) {
        float4 u0 = *(const float4*)(Srow + ks * 32);
        float4 u1 = *(const float4*)(Srow + ks * 32 + 4);
        sv[ks][0] = u0.x; sv[ks][1] = u0.y; sv[ks][2] = u0.z; sv[ks][3] = u0.w;
        sv[ks][4] = u1.x; sv[ks][5] = u1.y; sv[ks][6] = u1.z; sv[ks][7] = u1.w;
    }
    if (fq >= 2) {                    // cols 144..159: unwritten pad
#pragma unroll
        for (int j = 0; j < 8; j++) sv[4][j] = -1e30f;
    }
    float m = -1e30f;
#pragma unroll
    for (int ks = 0; ks < 5; ks++)
#pragma unroll
        for (int j = 0; j < 8; j++) m = fmaxf(m, sv[ks][j]);
    m = fmaxf(m, __shfl_xor(m, 16));
    m = fmaxf(m, __shfl_xor(m, 32));
    float sum = 0.f;
#pragma unroll
    for (int ks = 0; ks < 5; ks++)
#pragma unroll
        for (int j = 0; j < 8; j++) { float e = __expf(sv[ks][j] - m); sv[ks][j] = e; sum += e; }
    sum += __shfl_xor(sum, 16);
    sum += __shfl_xor(sum, 32);
    float inv = 1.f / sum;

    short8 a[5];     // P in A-frag layout: row fr, k-pos fq*8+j within 32-slice ks
#pragma unroll
    for (int ks = 0; ks < 5; ks++)
#pragma unroll
        for (int j = 0; j < 8; j++) a[ks][j] = (short)f2bf(sv[ks][j] * inv);

    // ---- PV: wave w owns E-cols [64w, 64w+64); loads clamped + batched (P=0 masks OOB)
    const int EC = w * 64;
    int tkc[5];
#pragma unroll
    for (int ks = 0; ks < 5; ks++) {
        int tok0 = R0 + ks * 32 + fq * 8;              // mod-8 aligned granule
        tkc[ks] = min(max(tok0, 0), L_SEQ - 8);        // clamp keeps 16B alignment
    }
    floatx4 oa[4] = {};
#pragma unroll
    for (int et = 0; et < 4; et++) {
        const unsigned short* vrow = vt + (size_t)(EC + et * 16 + fr) * 4096 + b * L_SEQ;
        short8 vfr[5];
#pragma unroll
        for (int ks = 0; ks < 5; ks++) vfr[ks] = *(const short8*)(vrow + tkc[ks]);
#pragma unroll
        for (int ks = 0; ks < 5; ks++)
            oa[et] = __builtin_amdgcn_mfma_f32_16x16x32_bf16(a[ks], vfr[ks], oa[et], 0, 0, 0);
    }

    float* op = out + (size_t)b * L_SEQ * E_DIM;
#pragma unroll
    for (int et = 0; et < 4; et++)
#pragma unroll
        for (int r = 0; r < 4; r++)
            op[(size_t)(Q0 + fq * 4 + r) * 512 + EC + et * 16 + fr] = oa[et][r];
}

// ---------------- launch ----------------
extern "C" void kernel_launch(void* const* d_in, const int* in_sizes, int n_in,
                              void* d_out, int out_size, void* d_ws, size_t ws_size,
                              hipStream_t stream)
{
    const float* x  = (const float*)d_in[0];
    const float* Wq = (const float*)d_in[1];
    const float* bq = (const float*)d_in[2];
    const float* Wk = (const float*)d_in[3];
    const float* bk = (const float*)d_in[4];
    const float* Wv = (const float*)d_in[5];
    const float* bv = (const float*)d_in[6];
    float* out = (float*)d_out;

    char* ws = (char*)d_ws;
    unsigned short* qb = (unsigned short*)(ws);                  // 4 MB bf16 q
    unsigned short* kb = (unsigned short*)(ws + 4194304);        // 4 MB bf16 k
    unsigned short* vt = (unsigned short*)(ws + 8388608);        // 4 MB bf16 v^T [e][tok]

    qkv_gemm<<<dim3(64, 8, 3), 256, 0, stream>>>(x, Wq, Wk, Wv, bq, bk, bv, qb, kb, vt);
    attn_fused<<<dim3(128, 2), 512, 0, stream>>>(qb, kb, vt, out);
}

// Round 8
// 112.007 us; speedup vs baseline: 1.0430x; 1.0285x over previous
//
#include <hip/hip_runtime.h>
#include <cstdint>
#include <cstddef>

#define L_SEQ 2048
#define E_DIM 512
#define B_SZ 2
#define WIN 64
#define SCALE_QK 0.044194173824159216f  // 1/sqrt(512)

typedef __attribute__((ext_vector_type(8))) short short8;
typedef __attribute__((ext_vector_type(4))) float floatx4;

__device__ __forceinline__ unsigned short f2bf(float f) {
    unsigned int u = __float_as_uint(f);
    u += 0x7FFFu + ((u >> 16) & 1u);
    return (unsigned short)(u >> 16);
}

// pack 8 fp32 -> 8 bf16 (RNE) via v_cvt_pk_bf16_f32 (proven passing R6/R7).
__device__ __forceinline__ uint4 pk8(const float4 lo, const float4 hi) {
    uint4 r;
    asm("v_cvt_pk_bf16_f32 %0, %1, %2" : "=v"(r.x) : "v"(lo.x), "v"(lo.y));
    asm("v_cvt_pk_bf16_f32 %0, %1, %2" : "=v"(r.y) : "v"(lo.z), "v"(lo.w));
    asm("v_cvt_pk_bf16_f32 %0, %1, %2" : "=v"(r.z) : "v"(hi.x), "v"(hi.y));
    asm("v_cvt_pk_bf16_f32 %0, %1, %2" : "=v"(r.w) : "v"(hi.z), "v"(hi.w));
    return r;
}

__device__ __forceinline__ void ld16cvt(const float* g, uint4& r0, uint4& r1) {
    float4 f0 = *(const float4*)(g);
    float4 f1 = *(const float4*)(g + 4);
    float4 f2 = *(const float4*)(g + 8);
    float4 f3 = *(const float4*)(g + 12);
    r0 = pk8(f0, f1);
    r1 = pk8(f2, f3);
}

// ---------------- fused cvt + QKV projection, z-loop inside block ----------
// grid (64 m, 8 n) = 512 blocks = 2/CU.  Per kt: stage A (x) ONCE + B for all
// three W's, one barrier, A-frags read once and reused across z (acc[3][2][2],
// fully unrolled).  bid = bx + 64*by => blocks sharing an m-tile sit on ONE
// XCD (bid%8 = bx%8): per-XCD working set = 1 MB x + 3 MB W (fp32) ~ 4 MB L2.
// fp32 staging traffic ~90 MB L2-resident vs R7's ~400 MB L3-bound (the
// measured +23 us regression).  Outputs bit-identical to the cvt pipeline.
#define ALD 72   // LDS row stride (bf16): 2-way conflicts max per 16-lane phase
__global__ __launch_bounds__(256, 2) void qkv_fused(
    const float* __restrict__ x,    // 4096 x 512 fp32
    const float* __restrict__ Wq, const float* __restrict__ Wk, const float* __restrict__ Wv,
    const float* __restrict__ bq, const float* __restrict__ bk, const float* __restrict__ bv,
    unsigned short* __restrict__ q, unsigned short* __restrict__ k,
    unsigned short* __restrict__ vt)
{
    __shared__ __align__(16) unsigned short As[64 * ALD];        // 9216 B (epilogue alias)
    __shared__ __align__(16) unsigned short Bs[3][64 * ALD];     // 27648 B

    const int t = threadIdx.x;
    const int w = t >> 6, l = t & 63;
    const int m0 = blockIdx.x * 64, n0 = blockIdx.y * 64;
    const float* Ws[3] = { Wq, Wk, Wv };

    floatx4 acc[3][2][2] = {};
    const int wm = (w >> 1) * 32, wn = (w & 1) * 32;
    const int fr = l & 15, fq = l >> 4, fk = fq * 8;

    const int srow = t >> 2, scol = (t & 3) * 16;           // 16 cols per thread
    const float* gA = x + (size_t)(m0 + srow) * 512 + scol;

    float bv_[3][2];
    {
        const float* bs[3] = { bq, bk, bv };
#pragma unroll
        for (int z = 0; z < 3; z++)
#pragma unroll
            for (int j = 0; j < 2; j++) bv_[z][j] = bs[z][n0 + wn + j * 16 + fr];
    }

    for (int kt = 0; kt < 8; kt++) {
        const int kk = kt * 64;
        uint4 r0, r1;
        ld16cvt(gA + kk, r0, r1);
        *(uint4*)&As[srow * ALD + scol]     = r0;
        *(uint4*)&As[srow * ALD + scol + 8] = r1;
#pragma unroll
        for (int z = 0; z < 3; z++) {
            ld16cvt(Ws[z] + (size_t)(n0 + srow) * 512 + scol + kk, r0, r1);
            *(uint4*)&Bs[z][srow * ALD + scol]     = r0;
            *(uint4*)&Bs[z][srow * ALD + scol + 8] = r1;
        }
        __syncthreads();

        short8 a[2][2];                                     // A-frags: read once, reuse 3x
#pragma unroll
        for (int i = 0; i < 2; i++)
#pragma unroll
            for (int kh = 0; kh < 2; kh++)
                a[i][kh] = *(const short8*)&As[(wm + i * 16 + fr) * ALD + kh * 32 + fk];
#pragma unroll
        for (int z = 0; z < 3; z++) {
            short8 bf[2][2];
#pragma unroll
            for (int j = 0; j < 2; j++)
#pragma unroll
                for (int kh = 0; kh < 2; kh++)
                    bf[j][kh] = *(const short8*)&Bs[z][(wn + j * 16 + fr) * ALD + kh * 32 + fk];
#pragma unroll
            for (int kh = 0; kh < 2; kh++)
#pragma unroll
                for (int i = 0; i < 2; i++)
#pragma unroll
                    for (int j = 0; j < 2; j++)
                        acc[z][i][j] = __builtin_amdgcn_mfma_f32_16x16x32_bf16(a[i][kh], bf[j][kh], acc[z][i][j], 0, 0, 0);
        }
        __syncthreads();
    }

    // epilogue per z: frags -> LDS tile (alias As) -> coalesced 16B stores
    unsigned short* Tl = As;
    const int tr = t >> 2, tc = (t & 3) * 16;
#pragma unroll
    for (int z = 0; z < 3; z++) {
        if (z) __syncthreads();                // T of previous z fully read
        if (z < 2) {
#pragma unroll
            for (int i = 0; i < 2; i++)
#pragma unroll
                for (int j = 0; j < 2; j++)
#pragma unroll
                    for (int r = 0; r < 4; r++)
                        Tl[(wm + i * 16 + fq * 4 + r) * ALD + wn + j * 16 + fr] =
                            f2bf(acc[z][i][j][r] + bv_[z][j]);
        } else {
#pragma unroll
            for (int i = 0; i < 2; i++)
#pragma unroll
                for (int j = 0; j < 2; j++)
#pragma unroll
                    for (int r = 0; r < 4; r++)
                        Tl[(wn + j * 16 + fr) * ALD + wm + i * 16 + fq * 4 + r] =
                            f2bf(acc[z][i][j][r] + bv_[z][j]);
        }
        __syncthreads();

        uint4 v0 = *(const uint4*)&Tl[tr * ALD + tc];
        uint4 v1 = *(const uint4*)&Tl[tr * ALD + tc + 8];
        if (z < 2) {
            unsigned short* out = (z == 0) ? q : k;
            *(uint4*)&out[(size_t)(m0 + tr) * 512 + n0 + tc]     = v0;
            *(uint4*)&out[(size_t)(m0 + tr) * 512 + n0 + tc + 8] = v1;
        } else {
            *(uint4*)&vt[(size_t)(n0 + tr) * 4096 + m0 + tc]     = v0;
            *(uint4*)&vt[(size_t)(n0 + tr) * 4096 + m0 + tc + 8] = v1;
        }
    }
}

// ---------------- fused attention: 8 waves per 16-row Q-tile ----------------
// Same as the R3/R4/R7 passing kernel, plus a bijective XCD chunk-swizzle of
// the Q-tile index (128 tiles % 8 XCDs == 0): each XCD owns 16 consecutive
// Q-tiles, so overlapping K/V windows become L2 hits.
#define SLD 164   // LDS row stride (fp32): 164%32=4 -> 2-way conflicts max on row reads
__global__ __launch_bounds__(512) void attn_fused(
    const unsigned short* __restrict__ qb, const unsigned short* __restrict__ kb,
    const unsigned short* __restrict__ vt, float* __restrict__ out)
{
    __shared__ __align__(16) float Sl[16 * SLD];   // 10.5 KB

    const int t = threadIdx.x;
    const int w = t >> 6, l = t & 63;
    const int fr = l & 15, fq = l >> 4;
    const int bx = blockIdx.x;
    const int Qt = (bx & 7) * 16 + (bx >> 3);      // XCD chunk-swizzle, bijective on 0..127
    const int Q0 = Qt * 16;
    const int b  = blockIdx.y;
    const int R0 = Q0 - WIN;

    // ---- scores: wave w handles n-tile(s) {w, w+8} (only wave 0 gets a second)
    {
        const unsigned short* qrow = qb + (size_t)(b * L_SEQ + Q0 + fr) * 512 + fq * 8;
        short8 qf[16];
#pragma unroll
        for (int ks = 0; ks < 16; ks++) qf[ks] = *(const short8*)(qrow + ks * 32);

        for (int nt = w; nt < 9; nt += 8) {
            const int tok = R0 + nt * 16 + fr;
            const bool kvalid = (tok >= 0) && (tok < L_SEQ);
            const int tokc = min(max(tok, 0), L_SEQ - 1);        // clamped: always a real row
            const unsigned short* krow = kb + (size_t)(b * L_SEQ + tokc) * 512 + fq * 8;

            floatx4 acc0 = {}, acc1 = {};                        // 2 chains (8-deep, not 16)
            short8 bfr[8];
#pragma unroll
            for (int ks = 0; ks < 8; ks++) bfr[ks] = *(const short8*)(krow + ks * 32);
#pragma unroll
            for (int ks = 0; ks < 8; ks++)
                acc0 = __builtin_amdgcn_mfma_f32_16x16x32_bf16(qf[ks], bfr[ks], acc0, 0, 0, 0);
#pragma unroll
            for (int ks = 0; ks < 8; ks++) bfr[ks] = *(const short8*)(krow + (8 + ks) * 32);
#pragma unroll
            for (int ks = 0; ks < 8; ks++)
                acc1 = __builtin_amdgcn_mfma_f32_16x16x32_bf16(qf[8 + ks], bfr[ks], acc1, 0, 0, 0);

            const int jg = nt * 16 + fr;
#pragma unroll
            for (int r = 0; r < 4; r++) {
                int qq = fq * 4 + r;    // C/D layout: col=lane&15, row=(lane>>4)*4+r
                bool valid = kvalid && (jg >= qq) && (jg <= qq + 128);
                Sl[qq * SLD + jg] = valid ? (acc0[r] + acc1[r]) * SCALE_QK : -1e30f;
            }
        }
    }
    __syncthreads();

    // ---- softmax (per-wave redundant): lane covers row fr, cols fq*8 + ks*32 + j
    const float* Srow = &Sl[fr * SLD + fq * 8];
    float sv[5][8];
#pragma unroll
    for (int ks = 0; ks < 5; ks++) {
        float4 u0 = *(const float4*)(Srow + ks * 32);
        float4 u1 = *(const float4*)(Srow + ks * 32 + 4);
        sv[ks][0] = u0.x; sv[ks][1] = u0.y; sv[ks][2] = u0.z; sv[ks][3] = u0.w;
        sv[ks][4] = u1.x; sv[ks][5] = u1.y; sv[ks][6] = u1.z; sv[ks][7] = u1.w;
    }
    if (fq >= 2) {                    // cols 144..159: unwritten pad
#pragma unroll
        for (int j = 0; j < 8; j++) sv[4][j] = -1e30f;
    }
    float m = -1e30f;
#pragma unroll
    for (int ks = 0; ks < 5; ks++)
#pragma unroll
        for (int j = 0; j < 8; j++) m = fmaxf(m, sv[ks][j]);
    m = fmaxf(m, __shfl_xor(m, 16));
    m = fmaxf(m, __shfl_xor(m, 32));
    float sum = 0.f;
#pragma unroll
    for (int ks = 0; ks < 5; ks++)
#pragma unroll
        for (int j = 0; j < 8; j++) { float e = __expf(sv[ks][j] - m); sv[ks][j] = e; sum += e; }
    sum += __shfl_xor(sum, 16);
    sum += __shfl_xor(sum, 32);
    float inv = 1.f / sum;

    short8 a[5];     // P in A-frag layout: row fr, k-pos fq*8+j within 32-slice ks
#pragma unroll
    for (int ks = 0; ks < 5; ks++)
#pragma unroll
        for (int j = 0; j < 8; j++) a[ks][j] = (short)f2bf(sv[ks][j] * inv);

    // ---- PV: wave w owns E-cols [64w, 64w+64); loads clamped + batched (P=0 masks OOB)
    const int EC = w * 64;
    int tkc[5];
#pragma unroll
    for (int ks = 0; ks < 5; ks++) {
        int tok0 = R0 + ks * 32 + fq * 8;              // mod-8 aligned granule
        tkc[ks] = min(max(tok0, 0), L_SEQ - 8);        // clamp keeps 16B alignment
    }
    floatx4 oa[4] = {};
#pragma unroll
    for (int et = 0; et < 4; et++) {
        const unsigned short* vrow = vt + (size_t)(EC + et * 16 + fr) * 4096 + b * L_SEQ;
        short8 vfr[5];
#pragma unroll
        for (int ks = 0; ks < 5; ks++) vfr[ks] = *(const short8*)(vrow + tkc[ks]);
#pragma unroll
        for (int ks = 0; ks < 5; ks++)
            oa[et] = __builtin_amdgcn_mfma_f32_16x16x32_bf16(a[ks], vfr[ks], oa[et], 0, 0, 0);
    }

    float* op = out + (size_t)b * L_SEQ * E_DIM;
#pragma unroll
    for (int et = 0; et < 4; et++)
#pragma unroll
        for (int r = 0; r < 4; r++)
            op[(size_t)(Q0 + fq * 4 + r) * 512 + EC + et * 16 + fr] = oa[et][r];
}

// ---------------- launch ----------------
extern "C" void kernel_launch(void* const* d_in, const int* in_sizes, int n_in,
                              void* d_out, int out_size, void* d_ws, size_t ws_size,
                              hipStream_t stream)
{
    const float* x  = (const float*)d_in[0];
    const float* Wq = (const float*)d_in[1];
    const float* bq = (const float*)d_in[2];
    const float* Wk = (const float*)d_in[3];
    const float* bk = (const float*)d_in[4];
    const float* Wv = (const float*)d_in[5];
    const float* bv = (const float*)d_in[6];
    float* out = (float*)d_out;

    char* ws = (char*)d_ws;
    unsigned short* qb = (unsigned short*)(ws);                  // 4 MB bf16 q
    unsigned short* kb = (unsigned short*)(ws + 4194304);        // 4 MB bf16 k
    unsigned short* vt = (unsigned short*)(ws + 8388608);        // 4 MB bf16 v^T [e][tok]

    qkv_fused<<<dim3(64, 8), 256, 0, stream>>>(x, Wq, Wk, Wv, bq, bk, bv, qb, kb, vt);
    attn_fused<<<dim3(128, 2), 512, 0, stream>>>(qb, kb, vt, out);
}